// Round 5
// baseline (544.283 us; speedup 1.0000x reference)
//
#include <hip/hip_runtime.h>

// Router_26817775796684 — MI355X/gfx950, round 7.
// conv3x3(SAME)+relu+meanpool+fc+softmax+adaptive-threshold+sigmoid-renorm, fused.
//
// Round-7 change (vs round 6): break per-chunk phase lockstep with an
// intra-wave register ping-pong pipeline.
//   Round 6 evidence: all pipes <35% busy, occupancy at cap, and 43% occ was
//   SLOWER per-sample than round 2's 22% -> latency chain, not TLP, binds.
//   Each chunk serialized {4 ds_read -> lgkm wait -> 16 MFMA -> vmcnt + 16
//   reg copies}; waves run phases in lockstep so LDS and MFMA pipes alternate
//   instead of overlapping.
//   * Unroll-2 K-loop, two named A/B register sets: phase issues chunk c+1's
//     ds_reads + B loads BEFORE chunk c's MFMAs (other set) -> LDS latency
//     fully covered by the previous MFMA burst; bcur=bnext copies gone.
//   * +64 VGPR ping-pong -> ~145 unified regs -> __launch_bounds__(256,3)
//     (cap 170, no spill). 3 waves/SIMD by design.
//   * roff formula is valid through kb=80; kb 81..83 clamp to 80 (B columns
//     are exact zeros; clamped A read stays inside the staged A region).

typedef _Float16 half8 __attribute__((ext_vector_type(8)));
typedef float    floatx4 __attribute__((ext_vector_type(4)));

#define A_SAMPLE  14400              // 100 rows * 144 B
#define LDS_P_OFF 28800              // pooled[2][128] fp32 after 2 A samples
#define LDS_TOTAL 29824

// Repacked B: half-element index i = h*43008 + c*2048 + l*32 + n*8 + j
//   (21 chunks * 4096 B per (h,c); 64 B per lane; 16 B per fragment)
__global__ void prep_weights(const float* __restrict__ cw, _Float16* __restrict__ Bw) {
  int i  = blockIdx.x * 256 + threadIdx.x;   // 0..86015 (half elements)
  int h  = (i >= 43008) ? 1 : 0;
  int r1 = i - h * 43008;
  int c  = r1 >> 11;                         // chunk 0..20
  int r2 = r1 & 2047;
  int l  = r2 >> 5;                          // lane 0..63
  int r3 = r2 & 31;
  int n  = r3 >> 3;                          // fragment 0..3
  int j  = r3 & 7;
  int quad = l >> 4, lane15 = l & 15;
  int col  = h * 64 + n * 16 + lane15;       // output channel 0..127
  int kdim = (c * 4 + quad) * 8 + j;         // K index 0..671
  int kb   = kdim >> 3;
  int s    = (kb * 57) >> 9;                 // kb/9, exact for 0..83
  int ci   = kdim - s * 72;
  float v = 0.f;
  if (s < 9 && ci < 68) {
    int ky = s / 3, kx = s - 3 * ky;
    v = cw[((col * 68 + ci) * 3 + ky) * 3 + kx];
  }
  Bw[i] = (_Float16)v;                       // pads are EXACT zeros (never NaN)
}

__device__ __forceinline__ int roff_of(int cc, int quad) {
  int kb = cc * 4 + quad;
  kb = (kb > 80) ? 80 : kb;           // kb 81..83: zero B columns; clamp keeps
                                      // the A read inside the staged region
  int s   = (kb * 57) >> 9;           // kb/9, exact for 0..83
  int rem = kb - s * 9;
  int dy  = (s * 11) >> 5;            // s/3
  int dx  = s - 3 * dy;
  return (dy * 10 + dx - 11) * 144 + rem * 16;   // affine shift offset
}

__global__ __launch_bounds__(256, 3) void router_main(
    const float* __restrict__ patch,
    const float* __restrict__ conv_b,
    const _Float16* __restrict__ Bw,
    const float* __restrict__ fc_w,
    const float* __restrict__ fc_b,
    const float* __restrict__ p_wmax,
    const float* __restrict__ p_went,
    const float* __restrict__ p_wgap,
    const float* __restrict__ p_thr,
    const int* __restrict__ p_epoch,
    float* __restrict__ out)
{
  __shared__ __align__(16) unsigned char lds[LDS_TOTAL];
  const int tid    = threadIdx.x;
  const int l      = tid & 63;
  const int w      = tid >> 6;      // wave 0..3
  const int lane15 = l & 15;
  const int quad   = l >> 4;
  const int sm     = w >> 1;        // sample within WG (0,1)
  const int h      = w & 1;         // N-half AND staging-half
  const int n0     = h * 64;
  const int n_s    = blockIdx.x * 2;

  // ---- zero-fill BORDER rows only (36 rows * 9 slots = 324 b128/sample),
  //      split by h. Interior rows are fully covered by staged block writes,
  //      so no cross-wave write-ordering is needed (all addresses disjoint).
  {
    unsigned char* abase = lds + sm * A_SAMPLE;
    float4 z4 = make_float4(0.f, 0.f, 0.f, 0.f);
    #pragma unroll
    for (int j0 = 0; j0 < 3; ++j0) {
      int jj = j0 * 64 + l;
      if (jj < 162) {
        int j   = h * 162 + jj;               // 0..323
        int ri  = j / 9;                      // border-row index 0..35
        int col = j - ri * 9;
        // ri 0..9 -> rows 0..9; ri 10..25 -> rows 10,19,20,29,...,80,89;
        // ri 26..35 -> rows 90..99
        int row = (ri < 10) ? ri
                : (ri < 26) ? ((((ri - 10) >> 1) + 1) * 10 + ((ri - 10) & 1) * 9)
                            : (ri + 64);
        *(float4*)(abase + row * 144 + col * 16) = z4;
      }
    }
  }
  // ---- stage interior: lane l = position p=(y,x) -> padded row (y+1)*10+(x+1).
  //      Wave h stages ci-blocks b = 2*bb + h (even/odd split, disjoint 16B slots).
  {
    const float* psrc = patch + (size_t)(n_s + sm) * 4352 + l;   // [ci][p] layout
    int y = l >> 3, x = l & 7;
    unsigned char* arow = lds + sm * A_SAMPLE + ((y + 1) * 10 + (x + 1)) * 144;
    #pragma unroll
    for (int bb = 0; bb < 5; ++bb) {
      int b = bb * 2 + h;                     // h=0: 0,2,4,6,8  h=1: 1,3,5,7,(9 skipped)
      if (b < 9) {
        half8 hh;
        #pragma unroll
        for (int j = 0; j < 8; ++j) {
          int ci = b * 8 + j;
          float v = (ci < 68) ? psrc[ci * 64] : 0.f;   // 256 B/instr coalesced
          hh[j] = (_Float16)v;
        }
        *(half8*)(arow + b * 16) = hh;
      }
    }
  }

  // ---- per-lane B base (repacked layout: contiguous 64 B per lane-chunk);
  //      issue B chunk 0 BEFORE the barrier (doesn't touch LDS). ----
  const _Float16* bb = Bw + h * 43008 + l * 32;
  half8 b0[4], b1[4];
  #pragma unroll
  for (int n = 0; n < 4; ++n) b0[n] = *(const half8*)(bb + n * 8);

  __syncthreads();

  // ---- loop-invariant A fragment base offsets (this wave's 4 M-tiles) ----
  int apos[4];
  #pragma unroll
  for (int t = 0; t < 4; ++t) {
    int p  = t * 16 + lane15;                             // position within sample
    int pp = ((p >> 3) + 1) * 10 + (p & 7) + 1;           // padded row
    apos[t] = sm * A_SAMPLE + pp * 144;
  }

  floatx4 acc[4][4];
  floatx4 zacc = {0.f, 0.f, 0.f, 0.f};
  #pragma unroll
  for (int t = 0; t < 4; ++t)
    #pragma unroll
    for (int n = 0; n < 4; ++n) acc[t][n] = zacc;

  // ---- prologue: A chunk 0 -> set0 ----
  half8 a0[4], a1[4];
  {
    int ro = roff_of(0, quad);
    #pragma unroll
    for (int t = 0; t < 4; ++t)
      a0[t] = *(const half8*)(lds + apos[t] + ro);
  }

  // ---- ping-pong K loop: 2 chunks/iter, prefetch-next-before-compute.
  //      Chunk c+1 loads issue before chunk c's MFMAs (other register set):
  //      LDS/global latency hides under the 16-MFMA burst; no reg copies. ----
  #pragma unroll 1
  for (int c = 0; c < 20; c += 2) {
    // prefetch chunk c+1 -> set1
    {
      #pragma unroll
      for (int n = 0; n < 4; ++n)
        b1[n] = *(const half8*)(bb + (c + 1) * 2048 + n * 8);
      int ro = roff_of(c + 1, quad);
      #pragma unroll
      for (int t = 0; t < 4; ++t)
        a1[t] = *(const half8*)(lds + apos[t] + ro);
    }
    // compute chunk c (set0)
    #pragma unroll
    for (int t = 0; t < 4; ++t)
      #pragma unroll
      for (int n = 0; n < 4; ++n)
        acc[t][n] = __builtin_amdgcn_mfma_f32_16x16x32_f16(a0[t], b0[n], acc[t][n], 0, 0, 0);

    // prefetch chunk c+2 -> set0 (c+2 <= 20; roff_of clamps kb 81..83)
    {
      #pragma unroll
      for (int n = 0; n < 4; ++n)
        b0[n] = *(const half8*)(bb + (c + 2) * 2048 + n * 8);
      int ro = roff_of(c + 2, quad);
      #pragma unroll
      for (int t = 0; t < 4; ++t)
        a0[t] = *(const half8*)(lds + apos[t] + ro);
    }
    // compute chunk c+1 (set1)
    #pragma unroll
    for (int t = 0; t < 4; ++t)
      #pragma unroll
      for (int n = 0; n < 4; ++n)
        acc[t][n] = __builtin_amdgcn_mfma_f32_16x16x32_f16(a1[t], b1[n], acc[t][n], 0, 0, 0);
  }

  // ---- tail: chunk 20 sits in set0 (kb=80 real; 81..83 zero B columns) ----
  #pragma unroll
  for (int t = 0; t < 4; ++t)
    #pragma unroll
    for (int n = 0; n < 4; ++n)
      acc[t][n] = __builtin_amdgcn_mfma_f32_16x16x32_f16(a0[t], b0[n], acc[t][n], 0, 0, 0);

  // ---- bias + relu + mean-pool (C layout: row = quad*4+reg, col = lane15) ----
  float bcoef[4];
  #pragma unroll
  for (int n = 0; n < 4; ++n) bcoef[n] = conv_b[n0 + n * 16 + lane15];

  float* pl = (float*)(lds + LDS_P_OFF);          // pooled[2][128]
  #pragma unroll
  for (int n = 0; n < 4; ++n) {
    float ssum = 0.f;
    #pragma unroll
    for (int t = 0; t < 4; ++t)
      #pragma unroll
      for (int r = 0; r < 4; ++r)
        ssum += fmaxf(acc[t][n][r] + bcoef[n], 0.f);
    ssum += __shfl_xor(ssum, 16);                 // sum the 4 quad partials
    ssum += __shfl_xor(ssum, 32);
    if (l < 16)
      pl[sm * 128 + n0 + n * 16 + lane15] = ssum * (1.f / 64.f);
  }
  __syncthreads();

  // ---- fused routing epilogue: wave w (w<2) handles sample (n_s + w) ----
  if (w < 2) {
    const float* plw = pl + w * 128;
    int e  = l >> 3;                               // expert 0..7
    int c8 = l & 7;
    float part = 0.f;
    #pragma unroll
    for (int m = 0; m < 16; ++m) {
      int co = c8 + 8 * m;
      part += plw[co] * fc_w[co * 8 + e];
    }
    part += __shfl_xor(part, 1);
    part += __shfl_xor(part, 2);
    part += __shfl_xor(part, 4);

    float lg[8];
    #pragma unroll
    for (int j = 0; j < 8; ++j) lg[j] = __shfl(part, j * 8) + fc_b[j];

    float mx = lg[0];
    #pragma unroll
    for (int j = 1; j < 8; ++j) mx = fmaxf(mx, lg[j]);
    float wgt[8]; float sum = 0.f;
    #pragma unroll
    for (int j = 0; j < 8; ++j) { wgt[j] = expf(lg[j] - mx); sum += wgt[j]; }
    float inv = 1.f / sum;
    #pragma unroll
    for (int j = 0; j < 8; ++j) wgt[j] *= inv;

    // sort descending — Batcher odd-even, 19 comparators
    float sw[8];
    #pragma unroll
    for (int j = 0; j < 8; ++j) sw[j] = wgt[j];
    #define CSD(i, j) { float hi_ = fmaxf(sw[i], sw[j]); float lo_ = fminf(sw[i], sw[j]); sw[i] = hi_; sw[j] = lo_; }
    CSD(0,1) CSD(2,3) CSD(4,5) CSD(6,7)
    CSD(0,2) CSD(1,3) CSD(4,6) CSD(5,7)
    CSD(1,2) CSD(5,6)
    CSD(0,4) CSD(1,5) CSD(2,6) CSD(3,7)
    CSD(2,4) CSD(3,5)
    CSD(1,2) CSD(3,4) CSD(5,6)
    #undef CSD

    float s1 = 0.f;
    #pragma unroll
    for (int j = 0; j < 8; ++j) s1 += wgt[j];
    float mean = s1 * 0.125f;
    float var = 0.f;
    #pragma unroll
    for (int j = 0; j < 8; ++j) { float d = wgt[j] - mean; var += d * d; }
    float stdv = sqrtf(var * (1.f / 7.f));          // ddof=1
    float ent = 0.f;
    #pragma unroll
    for (int j = 0; j < 8; ++j) ent -= wgt[j] * logf(wgt[j] + 1e-18f);

    float maxc  = 1.f - sw[0];
    float entc  = 1.f - ent * 0.48089834696298783f; // 1/log(8)
    float mrest = (sw[1] + sw[2] + sw[3] + sw[4]) * 0.25f;
    float gap   = (sw[0] - mrest) / (sw[0] + 1e-8f);
    gap = fminf(fmaxf(gap, 0.f), 1.f);
    float af = p_wmax[0] * maxc + p_went[0] * entc + p_wgap[0] * gap;
    float th = p_thr[0] * (0.5f + af);
    float mn  = fmaxf(0.05f, mean - 0.5f * stdv);
    float mxt = fminf(0.7f, sw[0] - 0.1f * stdv);
    th = fminf(fmaxf(th, mn), mxt);                 // jnp.clip: lower then upper
    th = fminf(th, sw[1] * 0.9f);                   // kth = sw[MIN_EXPERTS_ACTIVE-1]

    int epoch = p_epoch[0];
    float outv[8];
    if (epoch < 20) {
      #pragma unroll
      for (int j = 0; j < 8; ++j) outv[j] = 0.125f;
    } else {
      float tau = (epoch <= 25) ? fmaxf(0.1f, 1.0f - (float)(epoch - 20) * 0.18f) : 0.1f;
      // forward value of hard + stopgrad(soft-hard) == soft exactly
      float ssum = 0.f;
      #pragma unroll
      for (int j = 0; j < 8; ++j) {
        float sj = 1.f / (1.f + expf(-(wgt[j] - th) / tau));
        outv[j] = sj; ssum += sj;
      }
      float invs = 1.f / fmaxf(ssum, 1e-8f);
      #pragma unroll
      for (int j = 0; j < 8; ++j) outv[j] *= invs;
    }

    if (l < 8) {
      float mv = outv[0];
      #pragma unroll
      for (int j = 1; j < 8; ++j) mv = (l == j) ? outv[j] : mv;
      out[(n_s + w) * 8 + l] = mv;
    }
  }
}

extern "C" void kernel_launch(void* const* d_in, const int* in_sizes, int n_in,
                              void* d_out, int out_size, void* d_ws, size_t ws_size,
                              hipStream_t stream) {
  const float* patch  = (const float*)d_in[0];
  const float* conv_w = (const float*)d_in[1];
  const float* conv_b = (const float*)d_in[2];
  const float* fc_w   = (const float*)d_in[3];
  const float* fc_b   = (const float*)d_in[4];
  const float* wmax   = (const float*)d_in[5];
  const float* went   = (const float*)d_in[6];
  const float* wgap   = (const float*)d_in[7];
  const float* thr    = (const float*)d_in[8];
  const int*   epoch  = (const int*)d_in[10];
  float* outp = (float*)d_out;
  _Float16* Bw = (_Float16*)d_ws;                 // 2*21*64*64 B = 172,032 B of ws

  int N = in_sizes[0] / 4352;                     // 16384 samples
  prep_weights<<<336, 256, 0, stream>>>(conv_w, Bw);
  router_main<<<N / 2, 256, 0, stream>>>(patch, conv_b, Bw, fc_w, fc_b,
                                         wmax, went, wgap, thr, epoch, outp);
}

// Round 6
// 495.807 us; speedup vs baseline: 1.0978x; 1.0978x over previous
//
#include <hip/hip_runtime.h>

// Router_26817775796684 — MI355X/gfx950, round 8.
// conv3x3(SAME)+relu+meanpool+fc+softmax+adaptive-threshold+sigmoid-renorm, fused.
//
// Round-8 changes (vs round 7):
//   * REVERT to round-2 decomposition (best measured: 224 us): 4 samples/WG,
//     wave tile 128Mx64N, acc[8][4], 2 blocks/CU. Rounds 6/7 proved more
//     occupancy loses to per-wave amortization, and the compiler collapses
//     source-level ping-pong (VGPR_Count=64 showed the buffers were never live).
//   * A layout re-indexed [pos][72ci] -> [ci-block rem 0..8][100 pos] of 16-B
//     entries. Quad lanes now read CONTIGUOUS 16-B slots (stride 16 B,
//     conflict-free) instead of stride-144 (4-bank stride aliasing across
//     quads = the 2.15e7 SQ_LDS_BANK_CONFLICT seen in every round).
//     Same size (14400 B/sample), same affine shift: roff = rem*1600 +
//     (dy*10+dx-11)*16. Staging writes are also stride-16 contiguous.
//   * Keep round-6 repacked coalesced B (one base pointer, 64 B/lane/chunk).

typedef _Float16 half8 __attribute__((ext_vector_type(8)));
typedef float    floatx4 __attribute__((ext_vector_type(4)));

#define A_SAMPLE  14400              // 9 rem-blocks * 100 positions * 16 B
#define LDS_P_OFF 57600              // pooled[4][128] fp32 after 4 A samples
#define LDS_TOTAL 59648

// Repacked B: half-element index i = h*43008 + c*2048 + l*32 + n*8 + j
//   (21 chunks * 4096 B per (h,c); 64 B per lane; 16 B per fragment)
__global__ void prep_weights(const float* __restrict__ cw, _Float16* __restrict__ Bw) {
  int i  = blockIdx.x * 256 + threadIdx.x;   // 0..86015 (half elements)
  int h  = (i >= 43008) ? 1 : 0;
  int r1 = i - h * 43008;
  int c  = r1 >> 11;                         // chunk 0..20
  int r2 = r1 & 2047;
  int l  = r2 >> 5;                          // lane 0..63
  int r3 = r2 & 31;
  int n  = r3 >> 3;                          // fragment 0..3
  int j  = r3 & 7;
  int quad = l >> 4, lane15 = l & 15;
  int col  = h * 64 + n * 16 + lane15;       // output channel 0..127
  int kdim = (c * 4 + quad) * 8 + j;         // K index 0..671
  int kb   = kdim >> 3;
  int s    = (kb * 57) >> 9;                 // kb/9, exact for 0..83
  int ci   = kdim - s * 72;
  float v = 0.f;
  if (s < 9 && ci < 68) {
    int ky = s / 3, kx = s - 3 * ky;
    v = cw[((col * 68 + ci) * 3 + ky) * 3 + kx];
  }
  Bw[i] = (_Float16)v;                       // pads are EXACT zeros (never NaN)
}

__global__ __launch_bounds__(256, 2) void router_main(
    const float* __restrict__ patch,
    const float* __restrict__ conv_b,
    const _Float16* __restrict__ Bw,
    const float* __restrict__ fc_w,
    const float* __restrict__ fc_b,
    const float* __restrict__ p_wmax,
    const float* __restrict__ p_went,
    const float* __restrict__ p_wgap,
    const float* __restrict__ p_thr,
    const int* __restrict__ p_epoch,
    float* __restrict__ out)
{
  __shared__ __align__(16) unsigned char lds[LDS_TOTAL];
  const int tid    = threadIdx.x;
  const int l      = tid & 63;
  const int w      = tid >> 6;      // wave 0..3
  const int lane15 = l & 15;
  const int quad   = l >> 4;
  const int m_half = w >> 1;        // which sample-pair this wave computes
  const int n0     = (w & 1) * 64;  // N 64-half
  const int h      = w & 1;
  const int n_s    = blockIdx.x * 4;

  // ---- zero-fill own sample's BORDER entries: 9 rem-blocks * 36 = 324 slots.
  //      (Interior entries are fully covered by the staged writes below;
  //      all writes are by this wave only -> in-order, no hazards.) ----
  {
    unsigned char* abase = lds + w * A_SAMPLE;
    float4 z4 = make_float4(0.f, 0.f, 0.f, 0.f);
    #pragma unroll
    for (int j0 = 0; j0 < 6; ++j0) {
      int j = j0 * 64 + l;
      if (j < 324) {
        int rem = (j * 57) >> 11;            // j/36, exact for 0..323
        int e   = j - rem * 36;
        // e 0..9 -> row 0 (pp 0..9); e 10..19 -> row 9 (pp 90..99);
        // e 20..35 -> cols 0/9 of rows 1..8
        int pp = (e < 10) ? e
               : (e < 20) ? (80 + e)
               : ((((e - 20) >> 1) + 1) * 10 + ((e - 20) & 1) * 9);
        *(float4*)(abase + (rem * 100 + pp) * 16) = z4;
      }
    }
  }
  // ---- stage own sample: lane l = position p=(y,x) -> entry (b, pp),
  //      pp = (y+1)*10+(x+1). Entry stride 16 B -> conflict-free writes. ----
  {
    const float* psrc = patch + (size_t)(n_s + w) * 4352 + l;    // [ci][p] layout
    int y = l >> 3, x = l & 7;
    unsigned char* abase = lds + w * A_SAMPLE + ((y + 1) * 10 + (x + 1)) * 16;
    #pragma unroll
    for (int b = 0; b < 9; ++b) {           // 9 ci-blocks of 8 (68 real + 4 zero pad)
      half8 hh;
      #pragma unroll
      for (int j = 0; j < 8; ++j) {
        int ci = b * 8 + j;
        float v = (ci < 68) ? psrc[ci * 64] : 0.f;   // 256 B/instr coalesced
        hh[j] = (_Float16)v;
      }
      *(half8*)(abase + b * 1600) = hh;
    }
  }
  __syncthreads();

  // ---- loop-invariant A fragment base offsets (this wave's 8 M-tiles) ----
  int apos[8];
  #pragma unroll
  for (int t = 0; t < 8; ++t) {
    int p  = (t & 3) * 16 + lane15;                       // position within sample
    int pp = ((p >> 3) + 1) * 10 + (p & 7) + 1;           // padded position
    apos[t] = (m_half * 2 + (t >> 2)) * A_SAMPLE + pp * 16;
  }

  // ---- per-lane B base (repacked layout: contiguous 64 B per lane-chunk) ----
  const _Float16* bb = Bw + h * 43008 + l * 32;

  floatx4 acc[8][4];
  floatx4 zacc = {0.f, 0.f, 0.f, 0.f};
  #pragma unroll
  for (int t = 0; t < 8; ++t)
    #pragma unroll
    for (int n = 0; n < 4; ++n) acc[t][n] = zacc;

  // preload B chunk 0 (coalesced 1 KB/wave per fragment set)
  half8 bcur[4];
  #pragma unroll
  for (int n = 0; n < 4; ++n) bcur[n] = *(const half8*)(bb + n * 8);

  // ---- barrier-free K loop: 20 full chunks (kb = 4c+quad <= 79, all valid) ----
  #pragma unroll 4
  for (int c = 0; c < 20; ++c) {
    half8 bnext[4];
    #pragma unroll
    for (int n = 0; n < 4; ++n)
      bnext[n] = *(const half8*)(bb + (c + 1) * 2048 + n * 8);

    int kb  = c * 4 + quad;
    int s   = (kb * 57) >> 9;           // kb/9, exact for 0..83
    int rem = kb - s * 9;
    int dy  = (s * 11) >> 5;            // s/3
    int dx  = s - 3 * dy;
    int roff = rem * 1600 + (dy * 10 + dx - 11) * 16;      // affine shift offset

    half8 afr[8];
    #pragma unroll
    for (int t = 0; t < 8; ++t)
      afr[t] = *(const half8*)(lds + apos[t] + roff);

    #pragma unroll
    for (int t = 0; t < 8; ++t)
      #pragma unroll
      for (int n = 0; n < 4; ++n)
        acc[t][n] = __builtin_amdgcn_mfma_f32_16x16x32_f16(afr[t], bcur[n], acc[t][n], 0, 0, 0);

    #pragma unroll
    for (int n = 0; n < 4; ++n) bcur[n] = bnext[n];
  }

  // ---- tail chunk c=20 (bcur already holds it): kb=80 (quad 0) real;
  //      kb 81..83 have exact-zero B fragments, so A contents are
  //      irrelevant — clamp offset in-bounds (finite staged data). ----
  {
    // kb=80: s=8, rem=8, dy=dx=2 -> 8*1600 + 11*16 = 12976
    int roff = (quad == 0) ? 12976 : 0;
    half8 afr[8];
    #pragma unroll
    for (int t = 0; t < 8; ++t)
      afr[t] = *(const half8*)(lds + apos[t] + roff);
    #pragma unroll
    for (int t = 0; t < 8; ++t)
      #pragma unroll
      for (int n = 0; n < 4; ++n)
        acc[t][n] = __builtin_amdgcn_mfma_f32_16x16x32_f16(afr[t], bcur[n], acc[t][n], 0, 0, 0);
  }

  // ---- bias + relu + mean-pool (C layout: row = quad*4+reg, col = lane15) ----
  float bcoef[4];
  #pragma unroll
  for (int n = 0; n < 4; ++n) bcoef[n] = conv_b[n0 + n * 16 + lane15];

  float* pl = (float*)(lds + LDS_P_OFF);          // pooled[4][128]
  #pragma unroll
  for (int gl = 0; gl < 2; ++gl) {
    #pragma unroll
    for (int n = 0; n < 4; ++n) {
      float ssum = 0.f;
      #pragma unroll
      for (int tt = 0; tt < 4; ++tt) {
        int t = gl * 4 + tt;
        #pragma unroll
        for (int r = 0; r < 4; ++r)
          ssum += fmaxf(acc[t][n][r] + bcoef[n], 0.f);
      }
      ssum += __shfl_xor(ssum, 16);               // sum the 4 quad partials
      ssum += __shfl_xor(ssum, 32);
      if (l < 16) {
        int g = m_half * 2 + gl;
        pl[g * 128 + n0 + n * 16 + lane15] = ssum * (1.f / 64.f);
      }
    }
  }
  __syncthreads();

  // ---- fused routing epilogue: wave w handles sample (n_s + w) ----
  const float* plw = pl + w * 128;
  int e  = l >> 3;                                 // expert 0..7
  int c8 = l & 7;
  float part = 0.f;
  #pragma unroll
  for (int m = 0; m < 16; ++m) {
    int co = c8 + 8 * m;
    part += plw[co] * fc_w[co * 8 + e];
  }
  part += __shfl_xor(part, 1);
  part += __shfl_xor(part, 2);
  part += __shfl_xor(part, 4);

  float lg[8];
  #pragma unroll
  for (int j = 0; j < 8; ++j) lg[j] = __shfl(part, j * 8) + fc_b[j];

  float mx = lg[0];
  #pragma unroll
  for (int j = 1; j < 8; ++j) mx = fmaxf(mx, lg[j]);
  float wgt[8]; float sum = 0.f;
  #pragma unroll
  for (int j = 0; j < 8; ++j) { wgt[j] = expf(lg[j] - mx); sum += wgt[j]; }
  float inv = 1.f / sum;
  #pragma unroll
  for (int j = 0; j < 8; ++j) wgt[j] *= inv;

  // sort descending — Batcher odd-even, 19 comparators
  float sw[8];
  #pragma unroll
  for (int j = 0; j < 8; ++j) sw[j] = wgt[j];
  #define CSD(i, j) { float hi_ = fmaxf(sw[i], sw[j]); float lo_ = fminf(sw[i], sw[j]); sw[i] = hi_; sw[j] = lo_; }
  CSD(0,1) CSD(2,3) CSD(4,5) CSD(6,7)
  CSD(0,2) CSD(1,3) CSD(4,6) CSD(5,7)
  CSD(1,2) CSD(5,6)
  CSD(0,4) CSD(1,5) CSD(2,6) CSD(3,7)
  CSD(2,4) CSD(3,5)
  CSD(1,2) CSD(3,4) CSD(5,6)
  #undef CSD

  float s1 = 0.f;
  #pragma unroll
  for (int j = 0; j < 8; ++j) s1 += wgt[j];
  float mean = s1 * 0.125f;
  float var = 0.f;
  #pragma unroll
  for (int j = 0; j < 8; ++j) { float d = wgt[j] - mean; var += d * d; }
  float stdv = sqrtf(var * (1.f / 7.f));          // ddof=1
  float ent = 0.f;
  #pragma unroll
  for (int j = 0; j < 8; ++j) ent -= wgt[j] * logf(wgt[j] + 1e-18f);

  float maxc  = 1.f - sw[0];
  float entc  = 1.f - ent * 0.48089834696298783f; // 1/log(8)
  float mrest = (sw[1] + sw[2] + sw[3] + sw[4]) * 0.25f;
  float gap   = (sw[0] - mrest) / (sw[0] + 1e-8f);
  gap = fminf(fmaxf(gap, 0.f), 1.f);
  float af = p_wmax[0] * maxc + p_went[0] * entc + p_wgap[0] * gap;
  float th = p_thr[0] * (0.5f + af);
  float mn  = fmaxf(0.05f, mean - 0.5f * stdv);
  float mxt = fminf(0.7f, sw[0] - 0.1f * stdv);
  th = fminf(fmaxf(th, mn), mxt);                 // jnp.clip: lower then upper
  th = fminf(th, sw[1] * 0.9f);                   // kth = sw[MIN_EXPERTS_ACTIVE-1]

  int epoch = p_epoch[0];
  float outv[8];
  if (epoch < 20) {
    #pragma unroll
    for (int j = 0; j < 8; ++j) outv[j] = 0.125f;
  } else {
    float tau = (epoch <= 25) ? fmaxf(0.1f, 1.0f - (float)(epoch - 20) * 0.18f) : 0.1f;
    // forward value of hard + stopgrad(soft-hard) == soft exactly
    float ssum = 0.f;
    #pragma unroll
    for (int j = 0; j < 8; ++j) {
      float sj = 1.f / (1.f + expf(-(wgt[j] - th) / tau));
      outv[j] = sj; ssum += sj;
    }
    float invs = 1.f / fmaxf(ssum, 1e-8f);
    #pragma unroll
    for (int j = 0; j < 8; ++j) outv[j] *= invs;
  }

  if (l < 8) {
    float mv = outv[0];
    #pragma unroll
    for (int j = 1; j < 8; ++j) mv = (l == j) ? outv[j] : mv;
    out[(n_s + w) * 8 + l] = mv;
  }
}

extern "C" void kernel_launch(void* const* d_in, const int* in_sizes, int n_in,
                              void* d_out, int out_size, void* d_ws, size_t ws_size,
                              hipStream_t stream) {
  const float* patch  = (const float*)d_in[0];
  const float* conv_w = (const float*)d_in[1];
  const float* conv_b = (const float*)d_in[2];
  const float* fc_w   = (const float*)d_in[3];
  const float* fc_b   = (const float*)d_in[4];
  const float* wmax   = (const float*)d_in[5];
  const float* went   = (const float*)d_in[6];
  const float* wgap   = (const float*)d_in[7];
  const float* thr    = (const float*)d_in[8];
  const int*   epoch  = (const int*)d_in[10];
  float* outp = (float*)d_out;
  _Float16* Bw = (_Float16*)d_ws;                 // 2*21*64*64 B = 172,032 B of ws

  int N = in_sizes[0] / 4352;                     // 16384 samples
  prep_weights<<<336, 256, 0, stream>>>(conv_w, Bw);
  router_main<<<N / 4, 256, 0, stream>>>(patch, conv_b, Bw, fc_w, fc_b,
                                         wmax, went, wgap, thr, epoch, outp);
}